// Round 10
// baseline (363.859 us; speedup 1.0000x reference)
//
#include <hip/hip_runtime.h>
#include <hip/hip_bf16.h>

// out = data @ (mask*weight)^T + bias, via bf16 MFMA.
// Round 10: break the MFMA+LDS pipe serialization (R4..R9 all ~250us: time =
// MFMA 2484 + LDS 2304 cyc/tile, i.e. SUM not MAX) by removing B from LDS:
// B is pre-tiled to MFMA fragment layout by cvt_w and loaded global->VGPR
// (1KB coalesced per fragment). LDS carries only A (64KB traffic/tile).
// Schedule: R4 skeleton - 1 barrier/tile, quadrant af-prefetch, vmcnt(0) @ end.

#define GM 8192
#define GN 4096
#define GK 4096
#define NT (GK / 64)   // 64 K-tiles of BK=64

typedef __attribute__((ext_vector_type(8))) short short8;
typedef __attribute__((ext_vector_type(8))) short bf16x8;
typedef __attribute__((ext_vector_type(4))) float f32x4;

__device__ __forceinline__ short f2bf(float x) {
    unsigned u = __builtin_bit_cast(unsigned, x);
    u += 0x7fffu + ((u >> 16) & 1u);
    return (short)(u >> 16);
}

__device__ __forceinline__ void stage16(const short* g, short* l) {
    __builtin_amdgcn_global_load_lds(
        (const __attribute__((address_space(1))) unsigned int*)g,
        (__attribute__((address_space(3))) unsigned int*)l, 16, 0, 0);
}

// --- conversion: data f32 -> bf16 (row-major, unchanged) ---
__global__ void cvt_data_kernel(const float* __restrict__ in, short* __restrict__ out, long n) {
    long i0 = ((long)blockIdx.x * blockDim.x + threadIdx.x) * 8;
    long stride = (long)gridDim.x * blockDim.x * 8;
    for (long i = i0; i < n; i += stride) {
        float4 a = *(const float4*)(in + i);
        float4 b = *(const float4*)(in + i + 4);
        short8 o;
        o[0] = f2bf(a.x); o[1] = f2bf(a.y); o[2] = f2bf(a.z); o[3] = f2bf(a.w);
        o[4] = f2bf(b.x); o[5] = f2bf(b.y); o[6] = f2bf(b.z); o[7] = f2bf(b.w);
        *(short8*)(out + i) = o;
    }
}

// --- conversion: (mask*weight) f32 -> bf16, FRAGMENT-TILED layout ---
// Tiled index (shorts): ((col>>4)*128 + (k>>5))*512 + (((k>>3)&3)*16 + (col&15))*8 + (k&7)
// so a 16x16x32 B-fragment (co, ko) is 512 consecutive shorts (1KB), lane-ordered:
// lane l = (k_octet)*16 + col_low  ==  MFMA B operand layout. One coalesced
// global_load_dwordx4 per fragment per wave.
__global__ void cvt_w_kernel(const float* __restrict__ w, const float* __restrict__ m,
                             short* __restrict__ out) {
    long t0 = (long)blockIdx.x * blockDim.x + threadIdx.x;
    long stride = (long)gridDim.x * blockDim.x;
    for (long t = t0; t < 4096L * 512; t += stride) {   // (col, k-octet)
        const int col = (int)(t >> 9);
        const int ko8 = (int)(t & 511);
        const float* wp = w + (size_t)col * GK + ko8 * 8;
        const float* mp = m + (size_t)col * GK + ko8 * 8;
        float4 wa = *(const float4*)wp;
        float4 wb = *(const float4*)(wp + 4);
        float4 ma = *(const float4*)mp;
        float4 mb = *(const float4*)(mp + 4);
        short8 o;
        o[0] = f2bf(wa.x * ma.x); o[1] = f2bf(wa.y * ma.y);
        o[2] = f2bf(wa.z * ma.z); o[3] = f2bf(wa.w * ma.w);
        o[4] = f2bf(wb.x * mb.x); o[5] = f2bf(wb.y * mb.y);
        o[6] = f2bf(wb.z * mb.z); o[7] = f2bf(wb.w * mb.w);
        size_t oi = ((size_t)((col >> 4) * 128 + (ko8 >> 2)) * 64
                     + ((ko8 & 3) * 16 + (col & 15))) * 8;
        *(short8*)(out + oi) = o;
    }
}

// --- GEMM: A via LDS (R4 zero-conflict swizzle), B via global->VGPR ---
// LDS (shorts, 64KB): dbuf d at d*16384; within: A.kb0 +0, A.kb1 +8192.
// A block [256r][32c] bf16, 64B rows, stored q = logical q ^ ((((r>>3)&1)<<1)|((r>>1)&1)).
// Per tile T (db by parity): top: read af(q0,q1), stage A(T+1)->dbn (4 gload_lds),
// load B(T+1)->BN (8 coalesced dwordx4); then 4 quadrant MFMA clusters with
// af-prefetch one quadrant ahead (compiler-counted lgkm; no drains);
// vmcnt(0) + ONE barrier at tile end (all vmem ~2000cyc old by then).
__global__ __launch_bounds__(512, 2) void gemm_8w(const short* __restrict__ A,
                                                  const short* __restrict__ Bt,
                                                  const float* __restrict__ bias,
                                                  float* __restrict__ C) {
    __shared__ short lds[32768];  // 64 KB

    const int tid  = threadIdx.x;
    const int lane = tid & 63;
    const int wid  = tid >> 6;   // 0..7
    const int wr   = wid >> 2;   // 0..1  (wave row: 128 rows)
    const int wc   = wid & 3;    // 0..3  (wave col: 64 cols)

    // XCD-aware bijective swizzle: nwg = 512, % 8 == 0
    const int bid  = blockIdx.x;
    const int swz  = (bid & 7) * 64 + (bid >> 3);
    const int brow = (swz >> 4) << 8;   // 32 M-tiles
    const int bcol = (swz & 15) << 8;   // 16 N-tiles

    // ---- A staging constants (pre-swizzled source; linear LDS dest) ----
    const int trow = tid >> 2;
    const int qlog = (tid & 3) ^ ((((trow >> 3) & 1) << 1) | ((trow >> 1) & 1));

    // ---- A fragment-read constants (R4's measured-zero-conflict read) ----
    const int l15 = lane & 15;
    const int q   = lane >> 4;
    const int qx  = (((l15 >> 3) & 1) << 1) | ((l15 >> 1) & 1);
    const int foff = l15 * 32 + ((q ^ qx) << 3);
    const int aW = wr * 4096;           // + db + kb*8192 + m*512 + foff

    // ---- B global fragment base: frag (n,kb) of tile T at
    //      btb + n*65536 + (2T+kb)*512  (shorts), lane offset folded in ----
    const int co0 = (bcol >> 4) + wc * 4;
    const short* btb = Bt + (size_t)co0 * 65536 + lane * 8;

    f32x4 acc[8][4] = {};
    bf16x8 af0[4], af1[4], bA[8], bB[8];   // af: quad sets (mm*2+kb); b: n*2+kb

    auto stA = [&](int kb, int dbase, size_t kcol) {
        #pragma unroll
        for (int j = 0; j < 2; ++j)
            stage16(A + (size_t)(brow + j * 128 + trow) * GK + kcol + kb * 32 + qlog * 8,
                    &lds[dbase + kb * 8192 + j * 4096 + wid * 512]);
    };

#define RDQ(DST, DB, QD)                                                           \
    _Pragma("unroll")                                                              \
    for (int mm = 0; mm < 2; ++mm)                                                 \
      _Pragma("unroll")                                                            \
      for (int kb = 0; kb < 2; ++kb)                                               \
        DST[mm * 2 + kb] =                                                         \
            *(const bf16x8*)&lds[(DB) + kb * 8192 + aW + ((QD) * 2 + mm) * 512 + foff];

#define BLD(DST, T)                                                                \
    _Pragma("unroll")                                                              \
    for (int n = 0; n < 4; ++n)                                                    \
      _Pragma("unroll")                                                            \
      for (int kb = 0; kb < 2; ++kb)                                               \
        DST[n * 2 + kb] =                                                          \
            *(const bf16x8*)(btb + (size_t)n * 65536 + (size_t)(2 * (T) + kb) * 512);

#define MFMAQ(QD, AF, BC)                                                          \
    __builtin_amdgcn_s_setprio(1);                                                 \
    _Pragma("unroll")                                                              \
    for (int mm = 0; mm < 2; ++mm)                                                 \
      _Pragma("unroll")                                                            \
      for (int n = 0; n < 4; ++n)                                                  \
        _Pragma("unroll")                                                          \
        for (int kb = 0; kb < 2; ++kb)                                             \
          acc[(QD) * 2 + mm][n] = __builtin_amdgcn_mfma_f32_16x16x32_bf16(         \
              AF[mm * 2 + kb], BC[n * 2 + kb], acc[(QD) * 2 + mm][n], 0, 0, 0);    \
    __builtin_amdgcn_s_setprio(0);

#define TILE(T, DB, DBN, BC, BN)                                                   \
  {                                                                                 \
    const bool st = (T) + 1 < NT;                                                   \
    const size_t kn = (size_t)((T) + 1) * 64;                                       \
    RDQ(af0, DB, 0)                                                                 \
    RDQ(af1, DB, 1)                                                                 \
    if (st) { stA(0, DBN, kn); stA(1, DBN, kn); BLD(BN, (T) + 1) }                  \
    __builtin_amdgcn_sched_barrier(0);                                              \
    MFMAQ(0, af0, BC)                                                               \
    RDQ(af0, DB, 2)                                                                 \
    __builtin_amdgcn_sched_barrier(0);                                              \
    MFMAQ(1, af1, BC)                                                               \
    RDQ(af1, DB, 3)                                                                 \
    __builtin_amdgcn_sched_barrier(0);                                              \
    MFMAQ(2, af0, BC)                                                               \
    MFMAQ(3, af1, BC)                                                               \
    asm volatile("s_waitcnt vmcnt(0)" ::: "memory");                                \
    __builtin_amdgcn_s_barrier();                                                   \
    asm volatile("" ::: "memory");                                                  \
  }

    // ---- prologue: stage A(0)->db0, load B(0)->bA ----
    stA(0, 0, 0); stA(1, 0, 0);
    BLD(bA, 0)
    asm volatile("s_waitcnt vmcnt(0)" ::: "memory");
    __builtin_amdgcn_s_barrier();
    asm volatile("" ::: "memory");

    for (int T = 0; T < NT; T += 2) {
        TILE(T,     0,     16384, bA, bB)
        TILE(T + 1, 16384, 0,     bB, bA)
    }
#undef TILE
#undef MFMAQ
#undef BLD
#undef RDQ

    // ---- epilogue: C/D layout col = lane&15, row = (lane>>4)*4 + r ----
    #pragma unroll
    for (int n = 0; n < 4; ++n) {
        const int col = bcol + wc * 64 + n * 16 + l15;
        const float bv = bias[col];
        #pragma unroll
        for (int m = 0; m < 8; ++m) {
            const int rowb = brow + wr * 128 + m * 16 + (q << 2);
            #pragma unroll
            for (int r = 0; r < 4; ++r)
                C[(size_t)(rowb + r) * GN + col] = acc[m][n][r] + bv;
        }
    }
}

extern "C" void kernel_launch(void* const* d_in, const int* in_sizes, int n_in,
                              void* d_out, int out_size, void* d_ws, size_t ws_size,
                              hipStream_t stream) {
    const float* data   = (const float*)d_in[0];  // [8192,4096]
    const float* weight = (const float*)d_in[1];  // [4096,4096]
    const float* mask   = (const float*)d_in[2];  // [4096,4096]
    const float* bias   = (const float*)d_in[3];  // [4096]
    float* out = (float*)d_out;

    short* dataB = (short*)d_ws;                  // 64 MB bf16 data (row-major)
    short* wBt   = dataB + (size_t)GM * GK;       // 32 MB bf16 masked weight (frag-tiled)

    cvt_data_kernel<<<2048, 256, 0, stream>>>(data, dataB, (long)GM * GK);
    cvt_w_kernel<<<2048, 256, 0, stream>>>(weight, mask, wBt);

    // grid = (8192/256) * (4096/256) = 32 * 16 = 512 workgroups, 8 waves each
    gemm_8w<<<512, 512, 0, stream>>>(dataB, wBt, bias, out);
}

// Round 11
// 348.320 us; speedup vs baseline: 1.0446x; 1.0446x over previous
//
#include <hip/hip_runtime.h>
#include <hip/hip_bf16.h>

// out = data @ (mask*weight)^T + bias, via bf16 MFMA.
// Round 11: occupancy route. 256x128 tile, BK=32, 8 waves of 64x64 output,
// ring-3 LDS (72KB), ~115 VGPR -> 2 blocks/CU (4 waves/SIMD): inter-block TLP
// overlaps the MFMA and LDS pipes that lockstep 2-waves/SIMD serialized.
// R4's measured-zero-conflict swizzle; 1 barrier/tile; counted vmcnt(3).

#define GM 8192
#define GN 4096
#define GK 4096
#define NT (GK / 32)   // 128 K-tiles of BK=32

typedef __attribute__((ext_vector_type(8))) short short8;
typedef __attribute__((ext_vector_type(8))) short bf16x8;
typedef __attribute__((ext_vector_type(4))) float f32x4;

__device__ __forceinline__ short f2bf(float x) {
    unsigned u = __builtin_bit_cast(unsigned, x);
    u += 0x7fffu + ((u >> 16) & 1u);
    return (short)(u >> 16);
}

__device__ __forceinline__ void stage16(const short* g, short* l) {
    __builtin_amdgcn_global_load_lds(
        (const __attribute__((address_space(1))) unsigned int*)g,
        (__attribute__((address_space(3))) unsigned int*)l, 16, 0, 0);
}

// --- conversion: data f32 -> bf16 ---
__global__ void cvt_data_kernel(const float* __restrict__ in, short* __restrict__ out, long n) {
    long i0 = ((long)blockIdx.x * blockDim.x + threadIdx.x) * 8;
    long stride = (long)gridDim.x * blockDim.x * 8;
    for (long i = i0; i < n; i += stride) {
        float4 a = *(const float4*)(in + i);
        float4 b = *(const float4*)(in + i + 4);
        short8 o;
        o[0] = f2bf(a.x); o[1] = f2bf(a.y); o[2] = f2bf(a.z); o[3] = f2bf(a.w);
        o[4] = f2bf(b.x); o[5] = f2bf(b.y); o[6] = f2bf(b.z); o[7] = f2bf(b.w);
        *(short8*)(out + i) = o;
    }
}

// --- conversion: (mask * weight) f32 -> bf16 (row-major) ---
__global__ void cvt_w_kernel(const float* __restrict__ w, const float* __restrict__ m,
                             short* __restrict__ out, long n) {
    long i0 = ((long)blockIdx.x * blockDim.x + threadIdx.x) * 8;
    long stride = (long)gridDim.x * blockDim.x * 8;
    for (long i = i0; i < n; i += stride) {
        float4 wa = *(const float4*)(w + i);
        float4 wb = *(const float4*)(w + i + 4);
        float4 ma = *(const float4*)(m + i);
        float4 mb = *(const float4*)(m + i + 4);
        short8 o;
        o[0] = f2bf(wa.x * ma.x); o[1] = f2bf(wa.y * ma.y);
        o[2] = f2bf(wa.z * ma.z); o[3] = f2bf(wa.w * ma.w);
        o[4] = f2bf(wb.x * mb.x); o[5] = f2bf(wb.y * mb.y);
        o[6] = f2bf(wb.z * mb.z); o[7] = f2bf(wb.w * mb.w);
        *(short8*)(out + i) = o;
    }
}

// --- TLP bf16 NT GEMM ---
// LDS (shorts): slot s (0..2) at s*12288: A [256r][32c] at +0, B [128r][32c]
// at +8192. 64B rows, quarter-swizzle stored q = logical q ^
// ((((row>>3)&1)<<1)|((row>>1)&1))  (R4's measured-zero-conflict pattern).
//
// Per tile T: {stage tile T+2 into slot (T+2)%3 (3 gload_lds); ds_read
// af[4], bf[4] from slot T%3; 16 MFMA; vmcnt(3) [confirms tile T+1; last
// stages: vmcnt(0) at T=NT-2]; barrier}. Ring-3 WAR: slot (T+2)%3 was last
// read in tile T-1, separated by the T-1 end barrier. Prologue: stage(0),
// stage(1); vmcnt(3) confirms tile 0.
__global__ __launch_bounds__(512, 4) void gemm_tlp(const short* __restrict__ A,
                                                   const short* __restrict__ B,
                                                   const float* __restrict__ bias,
                                                   float* __restrict__ C) {
    __shared__ short lds[36864];  // 72 KB = 3 slots x 12288 shorts

    const int tid  = threadIdx.x;
    const int lane = tid & 63;
    const int wid  = tid >> 6;   // 0..7
    const int wr   = wid >> 1;   // 0..3  (wave row: 64 rows)
    const int wc   = wid & 1;    // 0..1  (wave col: 64 cols)

    // XCD-aware bijective swizzle: nwg = 1024, % 8 == 0
    const int bid  = blockIdx.x;
    const int swz  = (bid & 7) * 128 + (bid >> 3);
    const int brow = (swz >> 5) << 8;   // 32 M-tiles (256 rows)
    const int bcol = (swz & 31) << 7;   // 32 N-tiles (128 cols)

    // ---- staging constants (pre-swizzled global source; linear LDS dest) ----
    const int trow = tid >> 2;          // 0..127
    const int qlog = (tid & 3) ^ ((((trow >> 3) & 1) << 1) | ((trow >> 1) & 1));

    // ---- fragment-read constants (swizzled LDS read) ----
    const int l15 = lane & 15;
    const int q   = lane >> 4;
    const int qx  = (((l15 >> 3) & 1) << 1) | ((l15 >> 1) & 1);
    const int foff = l15 * 32 + ((q ^ qx) << 3);   // shorts
    const int aOff = wr * 2048 + foff;             // + slot + m*512
    const int bOff = 8192 + wc * 2048 + foff;      // + slot + n*512

    f32x4 acc[4][4] = {};

    auto stageAB = [&](int sb, size_t kcol) {
        #pragma unroll
        for (int j = 0; j < 2; ++j)
            stage16(A + (size_t)(brow + j * 128 + trow) * GK + kcol + qlog * 8,
                    &lds[sb + j * 4096 + wid * 512]);
        stage16(B + (size_t)(bcol + trow) * GK + kcol + qlog * 8,
                &lds[sb + 8192 + wid * 512]);
    };

    // ---- prologue: stage tiles 0,1; confirm tile 0 ----
    stageAB(0, 0);
    stageAB(12288, 32);
    asm volatile("s_waitcnt vmcnt(3)" ::: "memory");
    __builtin_amdgcn_s_barrier();
    asm volatile("" ::: "memory");

    int cur = 0, st2 = 2;
    for (int T = 0; T < NT; ++T) {
        const int cb = cur * 12288;
        const bool stg = (T + 2 < NT);
        if (stg) stageAB(st2 * 12288, (size_t)(T + 2) * 32);

        bf16x8 af[4], bf[4];
        #pragma unroll
        for (int m = 0; m < 4; ++m) af[m] = *(const bf16x8*)&lds[cb + aOff + m * 512];
        #pragma unroll
        for (int n = 0; n < 4; ++n) bf[n] = *(const bf16x8*)&lds[cb + bOff + n * 512];

        __builtin_amdgcn_s_setprio(1);
        #pragma unroll
        for (int m = 0; m < 4; ++m)
            #pragma unroll
            for (int n = 0; n < 4; ++n)
                acc[m][n] = __builtin_amdgcn_mfma_f32_16x16x32_bf16(af[m], bf[n], acc[m][n], 0, 0, 0);
        __builtin_amdgcn_s_setprio(0);

        if (stg)                { asm volatile("s_waitcnt vmcnt(3)" ::: "memory"); }
        else if (T + 2 == NT)   { asm volatile("s_waitcnt vmcnt(0)" ::: "memory"); }
        __builtin_amdgcn_s_barrier();
        asm volatile("" ::: "memory");

        if (++cur == 3) cur = 0;
        if (++st2 == 3) st2 = 0;
    }

    // ---- epilogue: C/D layout col = lane&15, row = (lane>>4)*4 + r ----
    #pragma unroll
    for (int n = 0; n < 4; ++n) {
        const int col = bcol + wc * 64 + n * 16 + l15;
        const float bv = bias[col];
        #pragma unroll
        for (int m = 0; m < 4; ++m) {
            const int rowb = brow + wr * 64 + m * 16 + (q << 2);
            #pragma unroll
            for (int r = 0; r < 4; ++r)
                C[(size_t)(rowb + r) * GN + col] = acc[m][n][r] + bv;
        }
    }
}

extern "C" void kernel_launch(void* const* d_in, const int* in_sizes, int n_in,
                              void* d_out, int out_size, void* d_ws, size_t ws_size,
                              hipStream_t stream) {
    const float* data   = (const float*)d_in[0];  // [8192,4096]
    const float* weight = (const float*)d_in[1];  // [4096,4096]
    const float* mask   = (const float*)d_in[2];  // [4096,4096]
    const float* bias   = (const float*)d_in[3];  // [4096]
    float* out = (float*)d_out;

    short* dataB = (short*)d_ws;                  // 64 MB bf16 data
    short* wB    = dataB + (size_t)GM * GK;       // 32 MB bf16 masked weight

    cvt_data_kernel<<<2048, 256, 0, stream>>>(data, dataB, (long)GM * GK);
    cvt_w_kernel<<<2048, 256, 0, stream>>>(weight, mask, wB, (long)GN * GK);

    // grid = (8192/256) * (4096/128) = 32 * 32 = 1024 workgroups, 8 waves each
    gemm_tlp<<<1024, 512, 0, stream>>>(dataB, wB, bias, out);
}